// Round 7
// baseline (505.837 us; speedup 1.0000x reference)
//
#include <hip/hip_runtime.h>
#include <cstddef>

#define HH 16
#define TT 512
#define LOG2E 1.44269504088896340736f

typedef float v2f __attribute__((ext_vector_type(2)));
typedef float v4f __attribute__((ext_vector_type(4)));

static __device__ __forceinline__ float fexp2(float x){ return __builtin_amdgcn_exp2f(x); }
static __device__ __forceinline__ float frcp (float x){ return __builtin_amdgcn_rcpf(x); }
static __device__ __forceinline__ float frsq (float x){ return __builtin_amdgcn_rsqf(x); }

// tanh(c) = 2/(1+exp(-2c)) - 1 ; saturates correctly (rcp(inf)=0)
static __device__ __forceinline__ float ftanh(float c){
    return frcp(1.0f + fexp2(c * (-2.0f*LOG2E))) * 2.0f - 1.0f;
}

// broadcast within each quad of lanes (single v_mov_b32_dpp)
#if __has_builtin(__builtin_amdgcn_mov_dpp)
template<int CTRL>
static __device__ __forceinline__ float qb(float v){
    return __builtin_bit_cast(float,
        __builtin_amdgcn_mov_dpp(__builtin_bit_cast(int,v), CTRL, 0xF, 0xF, true));
}
#else
template<int CTRL>
static __device__ __forceinline__ float qb(float v){
    return __builtin_bit_cast(float,
        __builtin_amdgcn_update_dpp(0, __builtin_bit_cast(int,v), CTRL, 0xF, 0xF, true));
}
#endif

static __device__ __forceinline__ v2f pkfma(v2f a, v2f b, v2f c){
    return __builtin_elementwise_fma(a, b, c);  // -> v_pk_fma_f32
}

// accumulate a 16-float dot into two v2f partials (8 pk_fma)
static __device__ __forceinline__ void dot16_acc(const v4f* a, const v4f* w, v2f& s0, v2f& s1){
    s0 = pkfma(a[0].lo, w[0].lo, s0);  s1 = pkfma(a[0].hi, w[0].hi, s1);
    s0 = pkfma(a[1].lo, w[1].lo, s0);  s1 = pkfma(a[1].hi, w[1].hi, s1);
    s0 = pkfma(a[2].lo, w[2].lo, s0);  s1 = pkfma(a[2].hi, w[2].hi, s1);
    s0 = pkfma(a[3].lo, w[3].lo, s0);  s1 = pkfma(a[3].hi, w[3].hi, s1);
}

static __device__ __forceinline__ void ld4(v4f* dst, const float* p){
    const v4f* q = (const v4f*)p;
    dst[0] = q[0]; dst[1] = q[1]; dst[2] = q[2]; dst[3] = q[3];
}

// One step of the fused 2-layer pipeline (R1-proven schedule).
// XU holds x(T+1) on entry; after its last use it is refilled with x(T+3)
// via 4 global_load_dwordx4 (VMEM pipe / vmcnt — decoupled from the
// lgkm-tracked h LDS round trips; 2-step prefetch distance ≈ 870 cyc
// covers the L3-resident x fetch latency).
#define STEP(XU, T) do {                                                     \
    /* ---- layer 1, step (T)+1 ---- */                                      \
    v2f p0 = {bias0, 0.f}, p1 = {0.f, 0.f};                                  \
    dot16_acc(XU, wih0, p0, p1);                                             \
    dot16_acc(h1a, whh0, p0, p1);                                            \
    v2f ps = p0 + p1;                                                        \
    float a1 = ps.x + ps.y;                                                  \
    float r1 = frcp(1.0f + fexp2(a1));                                       \
    float i1 = qb<0x00>(r1), f1 = qb<0x55>(r1);                              \
    float g1 = qb<0xAA>(r1), o1 = qb<0xFF>(r1);                              \
    float gs1 = __builtin_fmaf(g1, -4.0f*LOG2E, 2.0f*LOG2E);                 \
    cs1 = __builtin_fmaf(f1, cs1, i1 * gs1);                                 \
    float h1n = o1 * (frcp(1.0f + fexp2(cs1)) * 2.0f - 1.0f);                \
    h1w[k] = h1n;                       /* publish h1(T+1) */                \
    /* ---- layer 2 part A: h1(T) · W_ih1 (last use of h1a) ---- */          \
    v2f q0 = {bias1, 0.f}, q1 = {0.f, 0.f};                                  \
    dot16_acc(h1a, wih1, q0, q1);                                            \
    ld4(h1a, h1w);                      /* broadcast h1(T+1) [next iter] */  \
    /* refill XU with x((T)+3) — VMEM, used 2 iterations from now */         \
    {                                                                        \
        const int jn = ((T) + 3 < TT) ? ((T) + 3) : (TT - 1);                \
        ld4(XU, xg + (size_t)jn * HH);                                       \
    }                                                                        \
    /* ---- layer 2 part B: h2(T-1) · W_hh1 ---- */                          \
    dot16_acc(h2a, whh1, q0, q1);                                            \
    v2f qs = q0 + q1;                                                        \
    float a2 = qs.x + qs.y;                                                  \
    float r2 = frcp(1.0f + fexp2(a2));                                       \
    float i2 = qb<0x00>(r2), f2 = qb<0x55>(r2);                              \
    float g2 = qb<0xAA>(r2), o2 = qb<0xFF>(r2);                              \
    float gs2 = __builtin_fmaf(g2, -4.0f*LOG2E, 2.0f*LOG2E);                 \
    cs2 = __builtin_fmaf(f2, cs2, i2 * gs2);                                 \
    float h2n = o2 * (frcp(1.0f + fexp2(cs2)) * 2.0f - 1.0f);                \
    h2w[k] = h2n;                       /* publish h2(T) */                  \
    ld4(h2a, h2w);                      /* broadcast h2(T)  [next iter] */   \
} while (0)

// One wave per batch element; 64-thread (1-wave) blocks so the 4096 blocks
// stream through the CUs without a co-residency generation cliff.
// Lane l owns gate g=l&3 of hidden unit k=l>>2. Layer 1 runs ONE timestep
// ahead of layer 2 (R1-proven pipeline).
//
// This round: x moved OFF the LDS pipe. x rows are wave-uniform 64B lines,
// L3-resident (x = 128 MB < 256 MB L3); per-step they are fetched with
// global_load_dwordx4 into a register double-buffer (vmcnt-tracked, so the
// h-recurrence's lgkmcnt waits never serialize against them — the R4
// failure mode). LDS carries ONLY the h1/h2 publish/broadcast: DS ops drop
// from ~14 to 10 per step and per-CU LDS-queue pressure by ~40%, which is
// the best remaining explanation of the ~25% correlated VALU idle.
// __launch_bounds__(64,3): 3 waves/SIMD -> ~170-reg cap, the full ~150-reg
// live set (incl. 32 regs of x buffers) fits with zero spill.
__global__ __launch_bounds__(64, 3) void lstm_fused_kernel(
    const float* __restrict__ x,
    const float* __restrict__ W_ih0, const float* __restrict__ W_hh0,
    const float* __restrict__ b_ih0, const float* __restrict__ b_hh0,
    const float* __restrict__ W_ih1, const float* __restrict__ W_hh1,
    const float* __restrict__ b_ih1, const float* __restrict__ b_hh1,
    const float* __restrict__ W_proj, const float* __restrict__ b_proj,
    const float* __restrict__ ln_g, const float* __restrict__ ln_b,
    float* __restrict__ out)
{
    const int lane = threadIdx.x;    // 0..63
    const int b    = blockIdx.x;

    const int g   = lane & 3;        // 0=i 1=f 2=g 3=o
    const int k   = lane >> 2;       // hidden unit 0..15
    const int row = g * HH + k;      // row in [4H,H] weights (PyTorch order)

    // LDS: h1[16] + h2[16] publish/broadcast buffers only
    __shared__ float sh[64];
    float* h1w = sh;
    float* h2w = sh + 32;

    // activation input scale: sigmoid lanes -log2e, tanh(g) lane -2log2e.
    const bool  isg   = (g == 2);
    const float sc_in = isg ? (-2.0f * LOG2E) : (-LOG2E);

    // ---- weights into VGPRs as v4f, PRE-SCALED by sc_in ----
    v4f wih0[4], whh0[4], wih1[4], whh1[4];
#pragma unroll
    for (int q = 0; q < 4; ++q) {
        wih0[q] = ((const v4f*)(W_ih0 + row * HH))[q] * sc_in;
        whh0[q] = ((const v4f*)(W_hh0 + row * HH))[q] * sc_in;
        wih1[q] = ((const v4f*)(W_ih1 + row * HH))[q] * sc_in;
        whh1[q] = ((const v4f*)(W_hh1 + row * HH))[q] * sc_in;
    }
    const float bias0 = (b_ih0[row] + b_hh0[row]) * sc_in;
    const float bias1 = (b_ih1[row] + b_hh1[row]) * sc_in;

    const float* xg = x + (size_t)b * TT * HH;

    // ================= prologue =================
    v4f x0[4], xbA[4], xbB[4];
    ld4(x0,  xg);                  // x(0) for step 0
    ld4(xbA, xg + 1 * HH);         // x(1) for main-loop t=0
    ld4(xbB, xg + 2 * HH);         // x(2) for main-loop t=1

    float cs1, cs2 = 0.0f;         // cs = -2*log2e * c
    v4f h1a[4], h2a[4];
#pragma unroll
    for (int q = 0; q < 4; ++q) h2a[q] = (v4f)(0.f);

    // layer-1 step 0 (h1(-1) = 0: skip hh dot)
    {
        v2f p0 = {bias0, 0.f}, p1 = {0.f, 0.f};
        dot16_acc(x0, wih0, p0, p1);
        v2f ps = p0 + p1;
        float a1 = ps.x + ps.y;
        float r1 = frcp(1.0f + fexp2(a1));
        float i1 = qb<0x00>(r1), g1 = qb<0xAA>(r1), o1 = qb<0xFF>(r1);
        float gs1 = __builtin_fmaf(g1, -4.0f*LOG2E, 2.0f*LOG2E);  // -2L*tanh-gate
        cs1 = i1 * gs1;
        float h1n = o1 * (frcp(1.0f + fexp2(cs1)) * 2.0f - 1.0f);
        h1w[k] = h1n;
        ld4(h1a, h1w);             // broadcast h1(0)
    }

    // ================= main loop =================
    // iter t: layer1 computes h1(t+1) [XU=x(t+1), h1a=h1(t)];
    //         layer2 computes h2(t)   [h1a=h1(t), h2a=h2(t-1)]
    // x buffers alternate by parity; each STEP refills its own buffer with
    // x(t+3) (same parity -> consumed exactly 2 iterations later).
    for (int t = 0; t < TT; t += 2) {
        STEP(xbA, t);
        STEP(xbB, t + 1);
    }
    // (final iter t=511 computes a harmless finite h1(512) from clamped x;
    //  h2(511) — the value we need — is exact, and h2a now holds it)

    // ---- epilogue: z = h2(T-1) @ W_proj^T + b_proj ; LayerNorm ; tanh ----
    const int u = lane & 15;   // output unit (replicated x4 across the wave)
    v4f wp[4];
#pragma unroll
    for (int q = 0; q < 4; ++q) wp[q] = ((const v4f*)(W_proj + u * HH))[q];
    v2f z0 = {0.f, 0.f}, z1 = {0.f, 0.f};
    dot16_acc(h2a, wp, z0, z1);
    v2f zs = z0 + z1;
    float z = b_proj[u] + zs.x + zs.y;

    // stats across the 16-lane group (xor masks 1,2,4,8 stay in-group)
    float sacc = z;
    sacc += __shfl_xor(sacc, 1); sacc += __shfl_xor(sacc, 2);
    sacc += __shfl_xor(sacc, 4); sacc += __shfl_xor(sacc, 8);
    const float mu = sacc * (1.0f / 16.0f);

    const float d = z - mu;
    float q2 = d * d;
    q2 += __shfl_xor(q2, 1); q2 += __shfl_xor(q2, 2);
    q2 += __shfl_xor(q2, 4); q2 += __shfl_xor(q2, 8);
    const float var = q2 * (1.0f / 16.0f);

    const float rs  = frsq(var + 1e-5f);
    const float y   = d * rs * ln_g[u] + ln_b[u];
    const float res = ftanh(y);

    if (lane < 16) out[(size_t)b * HH + lane] = res;
}

extern "C" void kernel_launch(void* const* d_in, const int* in_sizes, int n_in,
                              void* d_out, int out_size, void* d_ws, size_t ws_size,
                              hipStream_t stream) {
    const float* x      = (const float*)d_in[0];
    const float* W_ih0  = (const float*)d_in[1];
    const float* W_hh0  = (const float*)d_in[2];
    const float* b_ih0  = (const float*)d_in[3];
    const float* b_hh0  = (const float*)d_in[4];
    const float* W_ih1  = (const float*)d_in[5];
    const float* W_hh1  = (const float*)d_in[6];
    const float* b_ih1  = (const float*)d_in[7];
    const float* b_hh1  = (const float*)d_in[8];
    const float* W_proj = (const float*)d_in[9];
    const float* b_proj = (const float*)d_in[10];
    const float* ln_g   = (const float*)d_in[11];
    const float* ln_b   = (const float*)d_in[12];
    float* out = (float*)d_out;

    const int B = in_sizes[0] / (TT * HH);   // 4096
    dim3 grid(B), block(64);                 // one 1-wave block per batch elem
    hipLaunchKernelGGL(lstm_fused_kernel, grid, block, 0, stream,
                       x, W_ih0, W_hh0, b_ih0, b_hh0,
                       W_ih1, W_hh1, b_ih1, b_hh1,
                       W_proj, b_proj, ln_g, ln_b, out);
}